// Round 16
// baseline (480.575 us; speedup 1.0000x reference)
//
#include <hip/hip_runtime.h>
#include <hip/hip_bf16.h>

// ---------------------------------------------------------------------------
// Trojan_GCN round 16:
//  - FUSED layer-1: gather (CSR rows -> 64KB LDS tile, swizzled packed hl)
//    + mgemm256 GEMM phase reading A from LDS. Eliminates the 51 MB agg1
//    round-trip and overlaps gather (BW) with GEMM (MFMA) across the
//    co-resident blocks (391 blocks <= 2/CU).
//  - B prefetch back to 1-deep (4-deep was neutral).
//  - rest as round 15 (u8 CSR partials, combined heads, gather-first layer 2)
// ---------------------------------------------------------------------------

typedef __attribute__((ext_vector_type(8))) short short8;
typedef __attribute__((ext_vector_type(4))) float f32x4;

#define NQ_CAP 12544   // LDS u32 capacity (>= N/4), 50.2 KB

union U16B { uint4 u; short8 s; };

// pack f32 -> (bf16 h | bf16 l)<<16,  v ~= h + l with ~2^-16 rel error
__device__ __forceinline__ unsigned pack_hl(float v)
{
    unsigned u = __builtin_bit_cast(unsigned, v);
    unsigned rb = u + 0x7fffu + ((u >> 16) & 1u);          // RNE for h
    float hf = __builtin_bit_cast(float, rb & 0xffff0000u);
    float r = v - hf;                                      // exact
    unsigned l = __builtin_bit_cast(unsigned, r) & 0xffff0000u;
    return (rb >> 16) | l;
}

__device__ __forceinline__ float decode_hl(unsigned u)
{
    float hf = __builtin_bit_cast(float, u << 16);
    float lf = __builtin_bit_cast(float, u & 0xffff0000u);
    return hf + lf;
}

// 8 packed u32 (2x uint4, k-ascending) -> short8 h frag + short8 l frag
__device__ __forceinline__ void unpack_hl(uint4 a, uint4 b, short8& h, short8& l)
{
    U16B H, L;
    H.u.x = (a.x & 0xffffu) | (a.y << 16);
    H.u.y = (a.z & 0xffffu) | (a.w << 16);
    H.u.z = (b.x & 0xffffu) | (b.y << 16);
    H.u.w = (b.z & 0xffffu) | (b.w << 16);
    L.u.x = (a.x >> 16) | (a.y & 0xffff0000u);
    L.u.y = (a.z >> 16) | (a.w & 0xffff0000u);
    L.u.z = (b.x >> 16) | (b.y & 0xffff0000u);
    L.u.w = (b.z >> 16) | (b.w & 0xffff0000u);
    h = H.s; l = L.s;
}

// ---- CSR build, no fabric atomics; u8-packed counts (4 nodes per u32) ----
__global__ __launch_bounds__(256) void hist_kernel(
    const int* __restrict__ src, const int* __restrict__ dst,
    unsigned* __restrict__ part_in, unsigned* __restrict__ part_out,
    int E, int chunk, int nq)
{
    __shared__ unsigned c32[NQ_CAP];
    const int b = blockIdx.x;
    const int* __restrict__ idx = blockIdx.y ? src : dst;
    unsigned* __restrict__ part = blockIdx.y ? part_out : part_in;

    for (int i = threadIdx.x; i < nq; i += 256) c32[i] = 0u;
    __syncthreads();

    const int base = b * chunk;
    const int lim = min(base + chunk, E);
    for (int e = base + threadIdx.x; e < lim; e += 256) {
        int n = idx[e];
        atomicAdd(&c32[n >> 2], 1u << ((n & 3) * 8));
    }
    __syncthreads();

    unsigned* __restrict__ o = part + (long)b * nq;
    for (int i = threadIdx.x; i < nq; i += 256) o[i] = c32[i];
}

// Parallel merge: 4 waves x 64 lanes; wave bg owns partials [bg*32, bg*32+32).
__global__ __launch_bounds__(256) void merge_kernel(
    unsigned* __restrict__ part_in, const unsigned* __restrict__ part_out,
    int* __restrict__ deg_in, float* __restrict__ norm_in,
    float* __restrict__ norm_out, int nq, int N)
{
    __shared__ unsigned gsum[4][64];
    const int il = threadIdx.x & 63;
    const int bg = threadIdx.x >> 6;
    const int i = blockIdx.x * 64 + il;
    const bool valid = (i < nq);

    unsigned p[32];
    unsigned run = 0u;
    if (valid) {
        #pragma unroll
        for (int j = 0; j < 32; ++j)
            p[j] = part_in[(long)(bg * 32 + j) * nq + i];
        #pragma unroll
        for (int j = 0; j < 32; ++j) run += p[j];
    }
    gsum[bg][il] = run;
    __syncthreads();

    unsigned base = 0u;
    #pragma unroll
    for (int g = 0; g < 4; ++g) {
        unsigned v = gsum[g][il];
        if (g < bg) base += v;
    }

    unsigned ro = 0u;
    if (valid) {
        #pragma unroll
        for (int j = 0; j < 32; ++j)
            ro += part_out[(long)(bg * 32 + j) * nq + i];
    }

    if (valid) {
        unsigned acc = base;
        #pragma unroll
        for (int j = 0; j < 32; ++j) {
            part_in[(long)(bg * 32 + j) * nq + i] = acc;  // exclusive prefix
            acc += p[j];
        }
        if (bg == 3) {   // acc = total deg_in, 4 nodes packed
            #pragma unroll
            for (int k = 0; k < 4; ++k) {
                int n = 4 * i + k;
                if (n < N) {
                    int dk = (int)((acc >> (8 * k)) & 0xffu);
                    deg_in[n] = dk;
                    norm_in[n] = rsqrtf(fmaxf((float)dk, 1.0f));
                }
            }
        }
    }

    __syncthreads();
    gsum[bg][il] = ro;
    __syncthreads();
    if (valid && bg == 0) {
        unsigned rt = gsum[0][il] + gsum[1][il] + gsum[2][il] + gsum[3][il];
        #pragma unroll
        for (int k = 0; k < 4; ++k) {
            int n = 4 * i + k;
            if (n < N)
                norm_out[n] = rsqrtf(fmaxf((float)((rt >> (8 * k)) & 0xffu), 1.0f));
        }
    }
}

// --- 3-kernel exclusive scan of deg_in into rowptr[1..N] ---
__global__ __launch_bounds__(256) void scan1_kernel(
    const int* __restrict__ deg, int* __restrict__ rowptr,
    int* __restrict__ bsum, int N)
{
    __shared__ int s[256];
    int t = threadIdx.x;
    int i = blockIdx.x * 256 + t;
    s[t] = (i < N) ? deg[i] : 0;
    __syncthreads();
    #pragma unroll
    for (int off = 1; off < 256; off <<= 1) {
        int v = (t >= off) ? s[t - off] : 0;
        __syncthreads();
        s[t] += v;
        __syncthreads();
    }
    if (i < N) rowptr[i + 1] = s[t];
    if (t == 255) bsum[blockIdx.x] = s[255];
}

__global__ __launch_bounds__(256) void scan2_kernel(int* __restrict__ bsum, int nb)
{
    __shared__ int s[256];
    int t = threadIdx.x;
    s[t] = (t < nb) ? bsum[t] : 0;
    __syncthreads();
    #pragma unroll
    for (int off = 1; off < 256; off <<= 1) {
        int v = (t >= off) ? s[t - off] : 0;
        __syncthreads();
        s[t] += v;
        __syncthreads();
    }
    if (t < nb) bsum[t] = s[t];
}

__global__ __launch_bounds__(256) void scan3_kernel(
    int* __restrict__ rowptr, const int* __restrict__ bsum, int N)
{
    int b = blockIdx.x;
    int i = b * 256 + threadIdx.x;
    if (i < N) {
        int add = (b > 0) ? bsum[b - 1] : 0;
        rowptr[i + 1] += add;
    }
    if (i == 0) rowptr[0] = 0;
}

// ecol[rowptr[dst[e]] + prefix + localslot] = src[e]; u8-packed LDS cursors.
__global__ __launch_bounds__(256) void fill2_kernel(
    const int* __restrict__ src, const int* __restrict__ dst,
    const int* __restrict__ rowptr, const unsigned* __restrict__ part_in,
    int* __restrict__ ecol, int E, int chunk, int nq)
{
    __shared__ unsigned c32[NQ_CAP];
    const int b = blockIdx.x;
    const unsigned* __restrict__ pref = part_in + (long)b * nq;
    for (int i = threadIdx.x; i < nq; i += 256) c32[i] = pref[i];
    __syncthreads();

    const int base = b * chunk;
    const int lim = min(base + chunk, E);
    for (int e = base + threadIdx.x; e < lim; e += 256) {
        int r = dst[e];
        unsigned old = atomicAdd(&c32[r >> 2], 1u << ((r & 3) * 8));
        unsigned slot = (old >> ((r & 3) * 8)) & 0xffu;
        ecol[rowptr[r] + (int)slot] = src[e];
    }
}

// weights: W [K,N] f32 -> packed hl-u32 [N,dstK] (transposed, strided dest)
struct WPrep {
    const float* w[6];
    unsigned* o[6];
    int K[6], N[6], dstK[6], base[7];
};

__global__ __launch_bounds__(256) void wprep_kernel(WPrep p)
{
    int t = blockIdx.x * 256 + threadIdx.x;
    if (t >= p.base[6]) return;
    int s = 0;
    while (t >= p.base[s + 1]) ++s;
    int loc = t - p.base[s];
    int K = p.K[s], N = p.N[s];
    int n = loc / K, k = loc - n * K;
    p.o[s][(long)n * p.dstK[s] + k] = pack_hl(p.w[s][(long)k * N + n]);
}

// ---------------------------------------------------------------------------
// FUSED layer-1 kernel: block = 128 rows.
// Phase 1: gather rows into LDS (packed hl-u32, granule-XOR swizzle).
// Phase 2: GEMM vs w1p (B streamed from L2, 1-deep prefetch), epilogue
//          h1s = pack(relu(ni*acc + b1) * no).
// LDS layout: row slot s, k-granule g (8 u32): u32 off = s*128 + (g^(s&3))*8.
// ---------------------------------------------------------------------------
__global__ __launch_bounds__(256) void fused1_kernel(
    const float* __restrict__ x, const float* __restrict__ nsrc,
    const int* __restrict__ rowptr, const int* __restrict__ ecol,
    const unsigned* __restrict__ Bp, const float* __restrict__ bias,
    const float* __restrict__ ni, const float* __restrict__ no,
    unsigned* __restrict__ Cp, int N)
{
    constexpr int K = 128;
    __shared__ unsigned sA[128 * 128];   // 64 KB

    const int tid = threadIdx.x;
    const int lane = tid & 63, wave = tid >> 6;
    const int row0 = blockIdx.x * 128;

    // ---- phase 1: gather 32 rows per wave into LDS ----
    {
        const int q = lane & 31;   // col quad
        const int h = lane >> 5;   // edge parity
        const float4* __restrict__ x4 = (const float4*)x;
        for (int rr = 0; rr < 32; ++rr) {
            const int slot = wave * 32 + rr;
            const int r = row0 + slot;
            float4 acc = make_float4(0.f, 0.f, 0.f, 0.f);
            if (r < N) {
                const int beg = rowptr[r], end = rowptr[r + 1];
                int k = beg + h;
                int sAi = (k < end) ? ecol[k] : -1;
                int sBi = (k + 2 < end) ? ecol[k + 2] : -1;
                float4 vA = make_float4(0.f, 0.f, 0.f, 0.f), vB = vA;
                float nA = 0.f, nB = 0.f;
                if (sAi >= 0) { vA = x4[(long)sAi * 32 + q]; nA = nsrc[sAi]; }
                if (sBi >= 0) { vB = x4[(long)sBi * 32 + q]; nB = nsrc[sBi]; }
                while (sAi >= 0) {
                    int sCi = (k + 4 < end) ? ecol[k + 4] : -1;
                    float4 vC = make_float4(0.f, 0.f, 0.f, 0.f);
                    float nC = 0.f;
                    if (sCi >= 0) { vC = x4[(long)sCi * 32 + q]; nC = nsrc[sCi]; }
                    acc.x = fmaf(vA.x, nA, acc.x);
                    acc.y = fmaf(vA.y, nA, acc.y);
                    acc.z = fmaf(vA.z, nA, acc.z);
                    acc.w = fmaf(vA.w, nA, acc.w);
                    sAi = sBi; vA = vB; nA = nB;
                    sBi = sCi; vB = vC; nB = nC;
                    k += 2;
                }
            }
            acc.x += __shfl(acc.x, lane ^ 32);
            acc.y += __shfl(acc.y, lane ^ 32);
            acc.z += __shfl(acc.z, lane ^ 32);
            acc.w += __shfl(acc.w, lane ^ 32);
            if (h == 0) {
                uint4 o;
                o.x = pack_hl(acc.x); o.y = pack_hl(acc.y);
                o.z = pack_hl(acc.z); o.w = pack_hl(acc.w);
                const int g = q >> 1, sub = q & 1;
                const int swzg = g ^ (slot & 3);
                *reinterpret_cast<uint4*>(&sA[slot * 128 + swzg * 8 + sub * 4]) = o;
            }
        }
    }
    __syncthreads();

    // ---- phase 2: GEMM (A from LDS, B streamed, 1-deep prefetch) ----
    const int l15 = lane & 15, l4 = lane >> 4;
    const long bbase = (long)l15 * K + l4 * 8;

    f32x4 acc[2][16];
    #pragma unroll
    for (int i = 0; i < 2; ++i)
        #pragma unroll
        for (int j = 0; j < 16; ++j)
            acc[i][j] = (f32x4){0.f, 0.f, 0.f, 0.f};

    short8 ah[2], al[2];
    uint4 b0 = *reinterpret_cast<const uint4*>(&Bp[bbase]);
    uint4 b1 = *reinterpret_cast<const uint4*>(&Bp[bbase + 4]);

    #pragma unroll
    for (int t = 0; t < 64; ++t) {
        const int c = t >> 4, j = t & 15;
        if (j == 0) {
            #pragma unroll
            for (int i = 0; i < 2; ++i) {
                const int slot = wave * 32 + i * 16 + l15;
                const int g = c * 4 + l4;
                const int swzg = g ^ (slot & 3);
                const int off = slot * 128 + swzg * 8;
                uint4 a0 = *reinterpret_cast<const uint4*>(&sA[off]);
                uint4 a1 = *reinterpret_cast<const uint4*>(&sA[off + 4]);
                unpack_hl(a0, a1, ah[i], al[i]);
            }
        }
        uint4 nb0, nb1;
        if (t + 1 < 64) {
            const int c1 = (t + 1) >> 4, j1 = (t + 1) & 15;
            const long na = bbase + (long)j1 * 16 * K + c1 * 32;
            nb0 = *reinterpret_cast<const uint4*>(&Bp[na]);
            nb1 = *reinterpret_cast<const uint4*>(&Bp[na + 4]);
        }
        short8 bh, bl;
        unpack_hl(b0, b1, bh, bl);
        #pragma unroll
        for (int i = 0; i < 2; ++i) {
            acc[i][j] = __builtin_amdgcn_mfma_f32_16x16x32_bf16(ah[i], bh, acc[i][j], 0, 0, 0);
            acc[i][j] = __builtin_amdgcn_mfma_f32_16x16x32_bf16(ah[i], bl, acc[i][j], 0, 0, 0);
            acc[i][j] = __builtin_amdgcn_mfma_f32_16x16x32_bf16(al[i], bh, acc[i][j], 0, 0, 0);
        }
        b0 = nb0; b1 = nb1;
    }

    #pragma unroll
    for (int i = 0; i < 2; ++i) {
        const int rbase = row0 + wave * 32 + i * 16 + l4 * 4;
        #pragma unroll
        for (int g = 0; g < 4; ++g) {
            const int row = rbase + g;
            if (row >= N) continue;
            const float niv = ni[row], nov = no[row];
            #pragma unroll
            for (int j = 0; j < 16; ++j) {
                const int col = j * 16 + l15;
                float v = fmaxf(fmaf(niv, acc[i][j][g], bias[col]), 0.f) * nov;
                Cp[(long)row * 256 + col] = pack_hl(v);
            }
        }
    }
}

// agg2ts[b,:] = pack( norm_in[r] * sum_{in-edges e of r} decode(h1s[src_e,:]) ),
// r = trig[b], D = 256; depth-2 pipeline.
__global__ __launch_bounds__(256) void gather_trig256_kernel(
    const unsigned* __restrict__ h1s, const int* __restrict__ trig,
    const float* __restrict__ norm_in,
    const int* __restrict__ rowptr, const int* __restrict__ ecol,
    unsigned* __restrict__ agg2ts, int T)
{
    const int wave = threadIdx.x >> 6;
    const int lane = threadIdx.x & 63;
    const int b = blockIdx.x * 4 + wave;
    if (b >= T) return;
    const int r = trig[b];
    const int beg = rowptr[r], end = rowptr[r + 1];
    const uint4* __restrict__ h4 = (const uint4*)h1s;   // row = 64 uint4

    float4 acc = make_float4(0.f, 0.f, 0.f, 0.f);
    int k = beg;
    int sA = (k < end) ? ecol[k] : -1;
    int sB = (k + 1 < end) ? ecol[k + 1] : -1;
    uint4 vA = make_uint4(0u, 0u, 0u, 0u), vB = vA;
    if (sA >= 0) vA = h4[(long)sA * 64 + lane];
    if (sB >= 0) vB = h4[(long)sB * 64 + lane];
    while (sA >= 0) {
        int sC = (k + 2 < end) ? ecol[k + 2] : -1;
        uint4 vC = make_uint4(0u, 0u, 0u, 0u);
        if (sC >= 0) vC = h4[(long)sC * 64 + lane];
        acc.x += decode_hl(vA.x);
        acc.y += decode_hl(vA.y);
        acc.z += decode_hl(vA.z);
        acc.w += decode_hl(vA.w);
        sA = sB; vA = vB;
        sB = sC; vB = vC;
        ++k;
    }
    const float ni = norm_in[r];
    uint4 o;
    o.x = pack_hl(acc.x * ni); o.y = pack_hl(acc.y * ni);
    o.z = pack_hl(acc.z * ni); o.w = pack_hl(acc.w * ni);
    *reinterpret_cast<uint4*>(&agg2ts[(long)b * 256 + lane * 4]) = o;
}

// Generic split-bf16 MFMA GEMM: B staged in LDS. TM=128. bias2 (if non-null)
// supplies bias for cols >= 128 (concat-head mode).
template<int TN, bool RELU, bool PACK_OUT>
__global__ __launch_bounds__(256) void mgemm_kernel(
    const unsigned* __restrict__ A, const unsigned* __restrict__ Bp,
    const float* __restrict__ bias, const float* __restrict__ bias2,
    const float* __restrict__ rowscale, const float* __restrict__ outscale,
    float* __restrict__ C, unsigned* __restrict__ Cp, int M, int N, int K)
{
    constexpr int IM = 2, KC = 32, TM = 128;
    constexpr int JF = TN / 16;
    constexpr int BLD = (TN * KC) / (4 * 256);

    __shared__ unsigned sB[KC * TN];

    const int tid = threadIdx.x;
    const int lane = tid & 63;
    const int wave = tid >> 6;
    const int l15 = lane & 15, l4 = lane >> 4;
    const int row0 = blockIdx.y * TM;
    const int col0 = blockIdx.x * TN;

    int bro[BLD], bgr[BLD];
    long bof[BLD];
    #pragma unroll
    for (int l = 0; l < BLD; ++l) {
        int idx = tid + 256 * l;
        bro[l] = idx % TN;
        bgr[l] = idx / TN;
        bof[l] = (long)(col0 + bro[l]) * K + bgr[l] * 4;
    }
    long aof[IM];
    #pragma unroll
    for (int i = 0; i < IM; ++i) {
        int r = row0 + wave * 32 + i * 16 + l15;
        if (r > M - 1) r = M - 1;
        aof[i] = (long)r * K + l4 * 8;
    }

    uint4 cB[BLD], nB[BLD], cA[IM][2], nA[IM][2];
    #pragma unroll
    for (int l = 0; l < BLD; ++l)
        cB[l] = *reinterpret_cast<const uint4*>(&Bp[bof[l]]);
    #pragma unroll
    for (int i = 0; i < IM; ++i) {
        cA[i][0] = *reinterpret_cast<const uint4*>(&A[aof[i]]);
        cA[i][1] = *reinterpret_cast<const uint4*>(&A[aof[i] + 4]);
    }

    f32x4 acc[IM][JF];
    #pragma unroll
    for (int i = 0; i < IM; ++i)
        #pragma unroll
        for (int j = 0; j < JF; ++j)
            acc[i][j] = (f32x4){0.f, 0.f, 0.f, 0.f};

    const int nc = K / KC;
    for (int c = 0; c < nc; ++c) {
        #pragma unroll
        for (int l = 0; l < BLD; ++l)
            *reinterpret_cast<uint4*>(&sB[(bgr[l] * TN + bro[l]) * 4]) = cB[l];
        __syncthreads();

        if (c + 1 < nc) {
            const int kc = (c + 1) * KC;
            #pragma unroll
            for (int l = 0; l < BLD; ++l)
                nB[l] = *reinterpret_cast<const uint4*>(&Bp[bof[l] + kc]);
            #pragma unroll
            for (int i = 0; i < IM; ++i) {
                nA[i][0] = *reinterpret_cast<const uint4*>(&A[aof[i] + kc]);
                nA[i][1] = *reinterpret_cast<const uint4*>(&A[aof[i] + kc + 4]);
            }
        }

        short8 ah[IM], al[IM];
        #pragma unroll
        for (int i = 0; i < IM; ++i)
            unpack_hl(cA[i][0], cA[i][1], ah[i], al[i]);

        #pragma unroll
        for (int j = 0; j < JF; ++j) {
            const int rowb = j * 16 + l15;
            uint4 b0 = *reinterpret_cast<const uint4*>(&sB[((2 * l4 + 0) * TN + rowb) * 4]);
            uint4 b1 = *reinterpret_cast<const uint4*>(&sB[((2 * l4 + 1) * TN + rowb) * 4]);
            short8 bh, bl;
            unpack_hl(b0, b1, bh, bl);
            #pragma unroll
            for (int i = 0; i < IM; ++i) {
                acc[i][j] = __builtin_amdgcn_mfma_f32_16x16x32_bf16(ah[i], bh, acc[i][j], 0, 0, 0);
                acc[i][j] = __builtin_amdgcn_mfma_f32_16x16x32_bf16(ah[i], bl, acc[i][j], 0, 0, 0);
                acc[i][j] = __builtin_amdgcn_mfma_f32_16x16x32_bf16(al[i], bh, acc[i][j], 0, 0, 0);
            }
        }
        __syncthreads();

        if (c + 1 < nc) {
            #pragma unroll
            for (int l = 0; l < BLD; ++l) cB[l] = nB[l];
            #pragma unroll
            for (int i = 0; i < IM; ++i) { cA[i][0] = nA[i][0]; cA[i][1] = nA[i][1]; }
        }
    }

    #pragma unroll
    for (int i = 0; i < IM; ++i) {
        const int rb = row0 + wave * 32 + i * 16 + l4 * 4;
        #pragma unroll
        for (int j = 0; j < JF; ++j) {
            const int col = col0 + j * 16 + l15;
            float bs = 0.0f;
            if (bias) bs = (bias2 && col >= 128) ? bias2[col - 128] : bias[col];
            #pragma unroll
            for (int g = 0; g < 4; ++g) {
                const int row = rb + g;
                if (row >= M) continue;
                float v = acc[i][j][g];
                if (rowscale) v *= rowscale[row];
                v += bs;
                if (RELU) v = fmaxf(v, 0.0f);
                if (outscale) v *= outscale[row];
                if (PACK_OUT) Cp[(long)row * N + col] = pack_hl(v);
                else          C[(long)row * N + col] = v;
            }
        }
    }
}

// Combined-heads final GEMM: A = tmpc [M,192] packed, B = wd1 [192,192]
// block-diag packed. cols 0..127 -> Cf+bf1; 128..191 -> Ce+be1.
__global__ __launch_bounds__(256) void mgemm_heads_kernel(
    const unsigned* __restrict__ A, const unsigned* __restrict__ Bp,
    const float* __restrict__ bf1, const float* __restrict__ be1,
    float* __restrict__ Cf, float* __restrict__ Ce, int M)
{
    constexpr int IM = 2, KC = 32, TM = 128, TN = 64, K = 192;
    constexpr int JF = TN / 16;
    constexpr int BLD = (TN * KC) / (4 * 256);

    __shared__ unsigned sB[KC * TN];

    const int tid = threadIdx.x;
    const int lane = tid & 63;
    const int wave = tid >> 6;
    const int l15 = lane & 15, l4 = lane >> 4;
    const int row0 = blockIdx.y * TM;
    const int col0 = blockIdx.x * TN;

    int bro[BLD], bgr[BLD];
    long bof[BLD];
    #pragma unroll
    for (int l = 0; l < BLD; ++l) {
        int idx = tid + 256 * l;
        bro[l] = idx % TN;
        bgr[l] = idx / TN;
        bof[l] = (long)(col0 + bro[l]) * K + bgr[l] * 4;
    }
    long aof[IM];
    #pragma unroll
    for (int i = 0; i < IM; ++i) {
        int r = row0 + wave * 32 + i * 16 + l15;
        if (r > M - 1) r = M - 1;
        aof[i] = (long)r * K + l4 * 8;
    }

    uint4 cB[BLD], nB[BLD], cA[IM][2], nA[IM][2];
    #pragma unroll
    for (int l = 0; l < BLD; ++l)
        cB[l] = *reinterpret_cast<const uint4*>(&Bp[bof[l]]);
    #pragma unroll
    for (int i = 0; i < IM; ++i) {
        cA[i][0] = *reinterpret_cast<const uint4*>(&A[aof[i]]);
        cA[i][1] = *reinterpret_cast<const uint4*>(&A[aof[i] + 4]);
    }

    f32x4 acc[IM][JF];
    #pragma unroll
    for (int i = 0; i < IM; ++i)
        #pragma unroll
        for (int j = 0; j < JF; ++j)
            acc[i][j] = (f32x4){0.f, 0.f, 0.f, 0.f};

    const int nc = K / KC;   // 6
    for (int c = 0; c < nc; ++c) {
        #pragma unroll
        for (int l = 0; l < BLD; ++l)
            *reinterpret_cast<uint4*>(&sB[(bgr[l] * TN + bro[l]) * 4]) = cB[l];
        __syncthreads();

        if (c + 1 < nc) {
            const int kc = (c + 1) * KC;
            #pragma unroll
            for (int l = 0; l < BLD; ++l)
                nB[l] = *reinterpret_cast<const uint4*>(&Bp[bof[l] + kc]);
            #pragma unroll
            for (int i = 0; i < IM; ++i) {
                nA[i][0] = *reinterpret_cast<const uint4*>(&A[aof[i] + kc]);
                nA[i][1] = *reinterpret_cast<const uint4*>(&A[aof[i] + kc + 4]);
            }
        }

        short8 ah[IM], al[IM];
        #pragma unroll
        for (int i = 0; i < IM; ++i)
            unpack_hl(cA[i][0], cA[i][1], ah[i], al[i]);

        #pragma unroll
        for (int j = 0; j < JF; ++j) {
            const int rowb = j * 16 + l15;
            uint4 b0 = *reinterpret_cast<const uint4*>(&sB[((2 * l4 + 0) * TN + rowb) * 4]);
            uint4 b1 = *reinterpret_cast<const uint4*>(&sB[((2 * l4 + 1) * TN + rowb) * 4]);
            short8 bh, bl;
            unpack_hl(b0, b1, bh, bl);
            #pragma unroll
            for (int i = 0; i < IM; ++i) {
                acc[i][j] = __builtin_amdgcn_mfma_f32_16x16x32_bf16(ah[i], bh, acc[i][j], 0, 0, 0);
                acc[i][j] = __builtin_amdgcn_mfma_f32_16x16x32_bf16(ah[i], bl, acc[i][j], 0, 0, 0);
                acc[i][j] = __builtin_amdgcn_mfma_f32_16x16x32_bf16(al[i], bh, acc[i][j], 0, 0, 0);
            }
        }
        __syncthreads();

        if (c + 1 < nc) {
            #pragma unroll
            for (int l = 0; l < BLD; ++l) cB[l] = nB[l];
            #pragma unroll
            for (int i = 0; i < IM; ++i) { cA[i][0] = nA[i][0]; cA[i][1] = nA[i][1]; }
        }
    }

    #pragma unroll
    for (int i = 0; i < IM; ++i) {
        const int rb = row0 + wave * 32 + i * 16 + l4 * 4;
        #pragma unroll
        for (int j = 0; j < JF; ++j) {
            const int col = col0 + j * 16 + l15;
            const bool isf = (col < 128);
            const float bs = isf ? bf1[col] : be1[col - 128];
            #pragma unroll
            for (int g = 0; g < 4; ++g) {
                const int row = rb + g;
                if (row >= M) continue;
                float v = acc[i][j][g] + bs;
                if (isf) Cf[(long)row * 128 + col] = v;
                else     Ce[(long)row * 64 + (col - 128)] = v;
            }
        }
    }
}

static inline long align8(long x) { return (x + 7) & ~7L; }

extern "C" void kernel_launch(void* const* d_in, const int* in_sizes, int n_in,
                              void* d_out, int out_size, void* d_ws, size_t ws_size,
                              hipStream_t stream)
{
    const float* features = (const float*)d_in[0];
    const int*   src      = (const int*)d_in[1];
    const int*   dst      = (const int*)d_in[2];
    const int*   trig     = (const int*)d_in[3];
    const float* W1  = (const float*)d_in[4];
    const float* b1  = (const float*)d_in[5];
    const float* W2  = (const float*)d_in[6];
    const float* b2  = (const float*)d_in[7];
    const float* Wf  = (const float*)d_in[8];
    const float* bf  = (const float*)d_in[9];
    const float* Wf1 = (const float*)d_in[10];
    const float* bf1 = (const float*)d_in[11];
    const float* We  = (const float*)d_in[12];
    const float* be  = (const float*)d_in[13];
    const float* We1 = (const float*)d_in[14];
    const float* be1 = (const float*)d_in[15];

    const int  d   = 128, h2d = 256, od = 64;
    const int  N   = in_sizes[0] / d;      // 50000
    const int  E   = in_sizes[1];          // 800000
    const int  T   = in_sizes[3];          // 4096
    const int  NB  = (N + 255) / 256;

    const int  HB    = 128;                 // histogram blocks (merge assumes 128)
    const int  chunk = (E + HB - 1) / HB;   // 6250
    const int  nq    = (N + 3) / 4;         // 12500 (<= NQ_CAP)

    // ---- workspace layout ----
    char* wsb = (char*)d_ws;
    long off = 0;  // bytes
    auto takeF = [&](long n) { float* p = (float*)(wsb + off); off += align8(n) * 4; return p; };
    auto takeI = [&](long n) { int*   p = (int*)  (wsb + off); off += align8(n) * 4; return p; };
    auto takeU = [&](long n) { unsigned* p = (unsigned*)(wsb + off); off += align8(n) * 4; return p; };

    float*    norm_out = takeF(N);
    float*    norm_in  = takeF(N);
    int*      deg_in   = takeI(N);
    int*      rowptr   = takeI(N + 1);
    int*      bsum     = takeI(256);
    int*      ecol     = takeI(E);
    unsigned* part_in  = takeU((long)HB * nq);      // 6.4 MB
    unsigned* part_out = takeU((long)HB * nq);      // 6.4 MB
    unsigned* h1s      = takeU((long)N * h2d);      // [N,256] packed
    unsigned* agg2ts   = takeU((long)T * h2d);      // [T,256] packed (ni folded)
    unsigned* h2t      = takeU((long)T * d);        // [T,128] packed
    unsigned* tmpc     = takeU((long)T * 192);      // [T,192] packed (heads mid)
    unsigned* w1p      = takeU((long)h2d * d);      // [256,128]
    unsigned* w2p      = takeU((long)d * h2d);      // [128,256]
    unsigned* wc       = takeU(192L * d);           // [192,128] = [Wf^T; We^T]
    unsigned* wd1      = takeU(192L * 192);         // [192,192] block-diag

    float* out_feat = (float*)d_out;              // [T,128]
    float* out_edge = out_feat + (long)T * d;     // [T,64]

    // ---- weight transpose + pack (wd1 zero-padded block-diagonal) ----
    hipMemsetAsync(wd1, 0, 192L * 192 * sizeof(unsigned), stream);
    WPrep wp;
    wp.w[0] = W1;  wp.o[0] = w1p;              wp.K[0] = d;   wp.N[0] = h2d; wp.dstK[0] = d;
    wp.w[1] = W2;  wp.o[1] = w2p;              wp.K[1] = h2d; wp.N[1] = d;   wp.dstK[1] = h2d;
    wp.w[2] = Wf;  wp.o[2] = wc;               wp.K[2] = d;   wp.N[2] = d;   wp.dstK[2] = d;
    wp.w[3] = We;  wp.o[3] = wc + 128 * d;     wp.K[3] = d;   wp.N[3] = od;  wp.dstK[3] = d;
    wp.w[4] = Wf1; wp.o[4] = wd1;              wp.K[4] = d;   wp.N[4] = d;   wp.dstK[4] = 192;
    wp.w[5] = We1; wp.o[5] = wd1 + 128L * 192 + 128;
                                               wp.K[5] = od;  wp.N[5] = od;  wp.dstK[5] = 192;
    wp.base[0] = 0;
    for (int i = 0; i < 6; ++i) wp.base[i + 1] = wp.base[i] + wp.K[i] * wp.N[i];
    wprep_kernel<<<dim3((wp.base[6] + 255) / 256), dim3(256), 0, stream>>>(wp);

    // ---- CSR build (no fabric atomics, u8-packed partials) ----
    hist_kernel<<<dim3(HB, 2), dim3(256), 0, stream>>>(
        src, dst, part_in, part_out, E, chunk, nq);
    merge_kernel<<<dim3((nq + 63) / 64), dim3(256), 0, stream>>>(
        part_in, part_out, deg_in, norm_in, norm_out, nq, N);
    scan1_kernel<<<dim3(NB), dim3(256), 0, stream>>>(deg_in, rowptr, bsum, N);
    scan2_kernel<<<dim3(1), dim3(256), 0, stream>>>(bsum, NB);
    scan3_kernel<<<dim3(NB), dim3(256), 0, stream>>>(rowptr, bsum, N);
    fill2_kernel<<<dim3(HB), dim3(256), 0, stream>>>(
        src, dst, rowptr, part_in, ecol, E, chunk, nq);

    const int GY = (N + 127) / 128;   // 391
    const int GT = T / 128;           // 32

    // ---- layer 1 (FUSED): h1s = pack(relu(ni*(A@(x*no))@W1 + b1)*no) ----
    fused1_kernel<<<dim3(GY), dim3(256), 0, stream>>>(
        features, norm_out, rowptr, ecol, w1p, b1, norm_in, norm_out, h1s, N);

    // ---- layer 2 (gather-first): agg2ts = pack(ni * A@h1s at trig rows);
    //      h2t = pack(relu(agg2ts @ W2 + b2))
    gather_trig256_kernel<<<dim3((T + 3) / 4), dim3(256), 0, stream>>>(
        h1s, trig, norm_in, rowptr, ecol, agg2ts, T);
    mgemm_kernel<64, true, true><<<dim3(d / 64, GT), dim3(256), 0, stream>>>(
        agg2ts, w2p, b2, nullptr, nullptr, nullptr, nullptr, h2t, T, d, h2d);

    // ---- heads (combined): tmpc = pack(relu(h2t @ [Wf|We] + [bf|be]))
    mgemm_kernel<64, true, true><<<dim3(192 / 64, GT), dim3(256), 0, stream>>>(
        h2t, wc, bf, be, nullptr, nullptr, nullptr, tmpc, T, 192, d);
    // [out_feat|out_edge] = tmpc @ blockdiag(Wf1, We1) + [bf1|be1]
    mgemm_heads_kernel<<<dim3(3, GT), dim3(256), 0, stream>>>(
        tmpc, wd1, bf1, be1, out_feat, out_edge, T);
}

// Round 17
// 265.606 us; speedup vs baseline: 1.8094x; 1.8094x over previous
//
#include <hip/hip_runtime.h>
#include <hip/hip_bf16.h>

// ---------------------------------------------------------------------------
// Trojan_GCN round 17: REVERT to round-12 configuration (best measured,
// 266 us). Round-16 fusion destroyed gather TLP (327 us); rounds 13-15
// micro-variants were neutral-to-negative.
//  - u16-packed LDS-histogram CSR build (no fabric atomics)
//  - depth-2 pipelined gather4 / gather_trig256
//  - mgemm256: TM=128, B streamed from L2 with 1-deep prefetch, no LDS
//  - layer-2 gather-first at trigger rows; combined MLP heads
// ---------------------------------------------------------------------------

typedef __attribute__((ext_vector_type(8))) short short8;
typedef __attribute__((ext_vector_type(4))) float f32x4;

#define NHALF_CAP 25088   // LDS u32 capacity (>= N/2), 100.4 KB

union U16B { uint4 u; short8 s; };

// pack f32 -> (bf16 h | bf16 l)<<16,  v ~= h + l with ~2^-16 rel error
__device__ __forceinline__ unsigned pack_hl(float v)
{
    unsigned u = __builtin_bit_cast(unsigned, v);
    unsigned rb = u + 0x7fffu + ((u >> 16) & 1u);          // RNE for h
    float hf = __builtin_bit_cast(float, rb & 0xffff0000u);
    float r = v - hf;                                      // exact
    unsigned l = __builtin_bit_cast(unsigned, r) & 0xffff0000u;
    return (rb >> 16) | l;
}

__device__ __forceinline__ float decode_hl(unsigned u)
{
    float hf = __builtin_bit_cast(float, u << 16);
    float lf = __builtin_bit_cast(float, u & 0xffff0000u);
    return hf + lf;
}

// 8 packed u32 (2x uint4, k-ascending) -> short8 h frag + short8 l frag
__device__ __forceinline__ void unpack_hl(uint4 a, uint4 b, short8& h, short8& l)
{
    U16B H, L;
    H.u.x = (a.x & 0xffffu) | (a.y << 16);
    H.u.y = (a.z & 0xffffu) | (a.w << 16);
    H.u.z = (b.x & 0xffffu) | (b.y << 16);
    H.u.w = (b.z & 0xffffu) | (b.w << 16);
    L.u.x = (a.x >> 16) | (a.y & 0xffff0000u);
    L.u.y = (a.z >> 16) | (a.w & 0xffff0000u);
    L.u.z = (b.x >> 16) | (b.y & 0xffff0000u);
    L.u.w = (b.z >> 16) | (b.w & 0xffff0000u);
    h = H.s; l = L.s;
}

// ---- CSR build, no fabric atomics ----
__global__ __launch_bounds__(256) void hist_kernel(
    const int* __restrict__ src, const int* __restrict__ dst,
    unsigned* __restrict__ part_in, unsigned* __restrict__ part_out,
    int E, int chunk, int nhalf)
{
    __shared__ unsigned c32[NHALF_CAP];
    const int b = blockIdx.x;
    const int* __restrict__ idx = blockIdx.y ? src : dst;
    unsigned* __restrict__ part = blockIdx.y ? part_out : part_in;

    for (int i = threadIdx.x; i < nhalf; i += 256) c32[i] = 0u;
    __syncthreads();

    const int base = b * chunk;
    const int lim = min(base + chunk, E);
    for (int e = base + threadIdx.x; e < lim; e += 256) {
        int n = idx[e];
        atomicAdd(&c32[n >> 1], (n & 1) ? 0x10000u : 1u);
    }
    __syncthreads();

    unsigned* __restrict__ o = part + (long)b * nhalf;
    for (int i = threadIdx.x; i < nhalf; i += 256) o[i] = c32[i];
}

// Parallel merge: 4 waves x 64 lanes; wave bg owns partials [bg*32, bg*32+32).
__global__ __launch_bounds__(256) void merge_kernel(
    unsigned* __restrict__ part_in, const unsigned* __restrict__ part_out,
    int* __restrict__ deg_in, float* __restrict__ norm_in,
    float* __restrict__ norm_out, int nhalf, int N)
{
    __shared__ unsigned gsum[4][64];
    const int il = threadIdx.x & 63;
    const int bg = threadIdx.x >> 6;
    const int i = blockIdx.x * 64 + il;
    const bool valid = (i < nhalf);

    unsigned p[32];
    unsigned run = 0u;
    if (valid) {
        #pragma unroll
        for (int j = 0; j < 32; ++j)
            p[j] = part_in[(long)(bg * 32 + j) * nhalf + i];
        #pragma unroll
        for (int j = 0; j < 32; ++j) run += p[j];
    }
    gsum[bg][il] = run;
    __syncthreads();

    unsigned base = 0u;
    #pragma unroll
    for (int g = 0; g < 4; ++g) {
        unsigned v = gsum[g][il];
        if (g < bg) base += v;
    }

    unsigned ro = 0u;
    if (valid) {
        #pragma unroll
        for (int j = 0; j < 32; ++j)
            ro += part_out[(long)(bg * 32 + j) * nhalf + i];
    }

    if (valid) {
        unsigned acc = base;
        #pragma unroll
        for (int j = 0; j < 32; ++j) {
            part_in[(long)(bg * 32 + j) * nhalf + i] = acc;  // exclusive prefix
            acc += p[j];
        }
        if (bg == 3) {
            int n0 = 2 * i, n1 = 2 * i + 1;
            int d0 = (int)(acc & 0xffffu), d1 = (int)(acc >> 16);
            deg_in[n0] = d0;
            norm_in[n0] = rsqrtf(fmaxf((float)d0, 1.0f));
            if (n1 < N) {
                deg_in[n1] = d1;
                norm_in[n1] = rsqrtf(fmaxf((float)d1, 1.0f));
            }
        }
    }

    __syncthreads();
    gsum[bg][il] = ro;
    __syncthreads();
    if (valid && bg == 0) {
        unsigned rt = gsum[0][il] + gsum[1][il] + gsum[2][il] + gsum[3][il];
        int n0 = 2 * i, n1 = 2 * i + 1;
        norm_out[n0] = rsqrtf(fmaxf((float)(rt & 0xffffu), 1.0f));
        if (n1 < N)
            norm_out[n1] = rsqrtf(fmaxf((float)(rt >> 16), 1.0f));
    }
}

// --- 3-kernel exclusive scan of deg_in into rowptr[1..N] ---
__global__ __launch_bounds__(256) void scan1_kernel(
    const int* __restrict__ deg, int* __restrict__ rowptr,
    int* __restrict__ bsum, int N)
{
    __shared__ int s[256];
    int t = threadIdx.x;
    int i = blockIdx.x * 256 + t;
    s[t] = (i < N) ? deg[i] : 0;
    __syncthreads();
    #pragma unroll
    for (int off = 1; off < 256; off <<= 1) {
        int v = (t >= off) ? s[t - off] : 0;
        __syncthreads();
        s[t] += v;
        __syncthreads();
    }
    if (i < N) rowptr[i + 1] = s[t];
    if (t == 255) bsum[blockIdx.x] = s[255];
}

__global__ __launch_bounds__(256) void scan2_kernel(int* __restrict__ bsum, int nb)
{
    __shared__ int s[256];
    int t = threadIdx.x;
    s[t] = (t < nb) ? bsum[t] : 0;
    __syncthreads();
    #pragma unroll
    for (int off = 1; off < 256; off <<= 1) {
        int v = (t >= off) ? s[t - off] : 0;
        __syncthreads();
        s[t] += v;
        __syncthreads();
    }
    if (t < nb) bsum[t] = s[t];
}

__global__ __launch_bounds__(256) void scan3_kernel(
    int* __restrict__ rowptr, const int* __restrict__ bsum, int N)
{
    int b = blockIdx.x;
    int i = b * 256 + threadIdx.x;
    if (i < N) {
        int add = (b > 0) ? bsum[b - 1] : 0;
        rowptr[i + 1] += add;
    }
    if (i == 0) rowptr[0] = 0;
}

__global__ __launch_bounds__(256) void fill2_kernel(
    const int* __restrict__ src, const int* __restrict__ dst,
    const int* __restrict__ rowptr, const unsigned* __restrict__ part_in,
    int* __restrict__ ecol, int E, int chunk, int nhalf)
{
    __shared__ unsigned c32[NHALF_CAP];
    const int b = blockIdx.x;
    const unsigned* __restrict__ pref = part_in + (long)b * nhalf;
    for (int i = threadIdx.x; i < nhalf; i += 256) c32[i] = pref[i];
    __syncthreads();

    const int base = b * chunk;
    const int lim = min(base + chunk, E);
    for (int e = base + threadIdx.x; e < lim; e += 256) {
        int r = dst[e];
        unsigned old = atomicAdd(&c32[r >> 1], (r & 1) ? 0x10000u : 1u);
        unsigned slot = (r & 1) ? (old >> 16) : (old & 0xffffu);
        ecol[rowptr[r] + (int)slot] = src[e];
    }
}

// weights: W [K,N] f32 -> packed hl-u32 [N,dstK] (transposed, strided dest)
struct WPrep {
    const float* w[6];
    unsigned* o[6];
    int K[6], N[6], dstK[6], base[7];
};

__global__ __launch_bounds__(256) void wprep_kernel(WPrep p)
{
    int t = blockIdx.x * 256 + threadIdx.x;
    if (t >= p.base[6]) return;
    int s = 0;
    while (t >= p.base[s + 1]) ++s;
    int loc = t - p.base[s];
    int K = p.K[s], N = p.N[s];
    int n = loc / K, k = loc - n * K;
    p.o[s][(long)n * p.dstK[s] + k] = pack_hl(p.w[s][(long)k * N + n]);
}

// agg1[r,:] = pack( sum_{in-edges e of r} x[src_e,:] * nsrc[src_e] )   (D=128)
// depth-2 pipeline: 2 row-loads in flight per lane group.
__global__ __launch_bounds__(256) void gather4_kernel(
    const float* __restrict__ x, const float* __restrict__ nsrc,
    const int* __restrict__ rowptr, const int* __restrict__ ecol,
    unsigned* __restrict__ out, int N)
{
    const int wave = threadIdx.x >> 6;
    const int lane = threadIdx.x & 63;
    const int r = blockIdx.x * 4 + wave;
    if (r >= N) return;
    const int q = lane & 31;   // col quad
    const int h = lane >> 5;   // edge parity
    const int beg = rowptr[r], end = rowptr[r + 1];
    const float4* __restrict__ x4 = (const float4*)x;

    float4 acc = make_float4(0.f, 0.f, 0.f, 0.f);
    int k = beg + h;
    int sA = (k < end) ? ecol[k] : -1;
    int sB = (k + 2 < end) ? ecol[k + 2] : -1;
    float4 vA = make_float4(0.f, 0.f, 0.f, 0.f), vB = vA;
    float nA = 0.f, nB = 0.f;
    if (sA >= 0) { vA = x4[(long)sA * 32 + q]; nA = nsrc[sA]; }
    if (sB >= 0) { vB = x4[(long)sB * 32 + q]; nB = nsrc[sB]; }
    while (sA >= 0) {
        int sC = (k + 4 < end) ? ecol[k + 4] : -1;
        float4 vC = make_float4(0.f, 0.f, 0.f, 0.f);
        float nC = 0.f;
        if (sC >= 0) { vC = x4[(long)sC * 32 + q]; nC = nsrc[sC]; }
        acc.x = fmaf(vA.x, nA, acc.x);
        acc.y = fmaf(vA.y, nA, acc.y);
        acc.z = fmaf(vA.z, nA, acc.z);
        acc.w = fmaf(vA.w, nA, acc.w);
        sA = sB; vA = vB; nA = nB;
        sB = sC; vB = vC; nB = nC;
        k += 2;
    }
    acc.x += __shfl(acc.x, lane ^ 32);
    acc.y += __shfl(acc.y, lane ^ 32);
    acc.z += __shfl(acc.z, lane ^ 32);
    acc.w += __shfl(acc.w, lane ^ 32);
    if (h == 0) {
        uint4 o;
        o.x = pack_hl(acc.x); o.y = pack_hl(acc.y);
        o.z = pack_hl(acc.z); o.w = pack_hl(acc.w);
        *reinterpret_cast<uint4*>(&out[(long)r * 128 + q * 4]) = o;
    }
}

// agg2ts[b,:] = pack( norm_in[r] * sum_{in-edges e of r} decode(h1s[src_e,:]) ),
// r = trig[b], D = 256; depth-2 pipeline.
__global__ __launch_bounds__(256) void gather_trig256_kernel(
    const unsigned* __restrict__ h1s, const int* __restrict__ trig,
    const float* __restrict__ norm_in,
    const int* __restrict__ rowptr, const int* __restrict__ ecol,
    unsigned* __restrict__ agg2ts, int T)
{
    const int wave = threadIdx.x >> 6;
    const int lane = threadIdx.x & 63;
    const int b = blockIdx.x * 4 + wave;
    if (b >= T) return;
    const int r = trig[b];
    const int beg = rowptr[r], end = rowptr[r + 1];
    const uint4* __restrict__ h4 = (const uint4*)h1s;   // row = 64 uint4

    float4 acc = make_float4(0.f, 0.f, 0.f, 0.f);
    int k = beg;
    int sA = (k < end) ? ecol[k] : -1;
    int sB = (k + 1 < end) ? ecol[k + 1] : -1;
    uint4 vA = make_uint4(0u, 0u, 0u, 0u), vB = vA;
    if (sA >= 0) vA = h4[(long)sA * 64 + lane];
    if (sB >= 0) vB = h4[(long)sB * 64 + lane];
    while (sA >= 0) {
        int sC = (k + 2 < end) ? ecol[k + 2] : -1;
        uint4 vC = make_uint4(0u, 0u, 0u, 0u);
        if (sC >= 0) vC = h4[(long)sC * 64 + lane];
        acc.x += decode_hl(vA.x);
        acc.y += decode_hl(vA.y);
        acc.z += decode_hl(vA.z);
        acc.w += decode_hl(vA.w);
        sA = sB; vA = vB;
        sB = sC; vB = vC;
        ++k;
    }
    const float ni = norm_in[r];
    uint4 o;
    o.x = pack_hl(acc.x * ni); o.y = pack_hl(acc.y * ni);
    o.z = pack_hl(acc.z * ni); o.w = pack_hl(acc.w * ni);
    *reinterpret_cast<uint4*>(&agg2ts[(long)b * 256 + lane * 4]) = o;
}

// Layer-1 GEMM: A [M,128] packed u32, B = w1p [256,128] packed u32 (L2-hot,
// streamed straight to fragments), C = h1s [M,256] packed. NO LDS/barriers.
__global__ __launch_bounds__(256) void mgemm256_kernel(
    const unsigned* __restrict__ A, const unsigned* __restrict__ Bp,
    const float* __restrict__ bias, const float* __restrict__ ni,
    const float* __restrict__ no, unsigned* __restrict__ Cp, int M)
{
    constexpr int K = 128;
    const int tid = threadIdx.x;
    const int lane = tid & 63, wave = tid >> 6;
    const int l15 = lane & 15, l4 = lane >> 4;
    const int row0 = blockIdx.x * 128;

    long aof[2];
    #pragma unroll
    for (int i = 0; i < 2; ++i) {
        int r = row0 + wave * 32 + i * 16 + l15;
        if (r > M - 1) r = M - 1;
        aof[i] = (long)r * K + l4 * 8;
    }
    const long bbase = (long)l15 * K + l4 * 8;

    uint4 abuf[2][2][2];
    #pragma unroll
    for (int i = 0; i < 2; ++i) {
        abuf[0][i][0] = *reinterpret_cast<const uint4*>(&A[aof[i] + 0]);
        abuf[0][i][1] = *reinterpret_cast<const uint4*>(&A[aof[i] + 4]);
        abuf[1][i][0] = *reinterpret_cast<const uint4*>(&A[aof[i] + 32]);
        abuf[1][i][1] = *reinterpret_cast<const uint4*>(&A[aof[i] + 36]);
    }

    f32x4 acc[2][16];
    #pragma unroll
    for (int i = 0; i < 2; ++i)
        #pragma unroll
        for (int j = 0; j < 16; ++j)
            acc[i][j] = (f32x4){0.f, 0.f, 0.f, 0.f};

    short8 ah[2], al[2];
    uint4 b0 = *reinterpret_cast<const uint4*>(&Bp[bbase]);
    uint4 b1 = *reinterpret_cast<const uint4*>(&Bp[bbase + 4]);

    #pragma unroll
    for (int t = 0; t < 64; ++t) {
        const int c = t >> 4, j = t & 15;
        if (j == 0) {
            const int cp = c & 1;
            unpack_hl(abuf[cp][0][0], abuf[cp][0][1], ah[0], al[0]);
            unpack_hl(abuf[cp][1][0], abuf[cp][1][1], ah[1], al[1]);
            if (c + 2 < 4) {
                #pragma unroll
                for (int i = 0; i < 2; ++i) {
                    abuf[cp][i][0] = *reinterpret_cast<const uint4*>(&A[aof[i] + (c + 2) * 32]);
                    abuf[cp][i][1] = *reinterpret_cast<const uint4*>(&A[aof[i] + (c + 2) * 32 + 4]);
                }
            }
        }
        uint4 nb0, nb1;
        if (t + 1 < 64) {
            const int c1 = (t + 1) >> 4, j1 = (t + 1) & 15;
            const long na = bbase + (long)j1 * 16 * K + c1 * 32;
            nb0 = *reinterpret_cast<const uint4*>(&Bp[na]);
            nb1 = *reinterpret_cast<const uint4*>(&Bp[na + 4]);
        }
        short8 bh, bl;
        unpack_hl(b0, b1, bh, bl);
        #pragma unroll
        for (int i = 0; i < 2; ++i) {
            acc[i][j] = __builtin_amdgcn_mfma_f32_16x16x32_bf16(ah[i], bh, acc[i][j], 0, 0, 0);
            acc[i][j] = __builtin_amdgcn_mfma_f32_16x16x32_bf16(ah[i], bl, acc[i][j], 0, 0, 0);
            acc[i][j] = __builtin_amdgcn_mfma_f32_16x16x32_bf16(al[i], bh, acc[i][j], 0, 0, 0);
        }
        b0 = nb0; b1 = nb1;
    }

    #pragma unroll
    for (int i = 0; i < 2; ++i) {
        const int rbase = row0 + wave * 32 + i * 16 + l4 * 4;
        #pragma unroll
        for (int g = 0; g < 4; ++g) {
            const int row = rbase + g;
            if (row >= M) continue;
            const float niv = ni[row], nov = no[row];
            #pragma unroll
            for (int j = 0; j < 16; ++j) {
                const int col = j * 16 + l15;
                float v = fmaxf(fmaf(niv, acc[i][j][g], bias[col]), 0.f) * nov;
                Cp[(long)row * 256 + col] = pack_hl(v);
            }
        }
    }
}

// Generic split-bf16 MFMA GEMM: B staged in LDS. TM=128. bias2 (if non-null)
// supplies bias for cols >= 128 (concat-head mode).
template<int TN, bool RELU, bool PACK_OUT>
__global__ __launch_bounds__(256) void mgemm_kernel(
    const unsigned* __restrict__ A, const unsigned* __restrict__ Bp,
    const float* __restrict__ bias, const float* __restrict__ bias2,
    const float* __restrict__ rowscale, const float* __restrict__ outscale,
    float* __restrict__ C, unsigned* __restrict__ Cp, int M, int N, int K)
{
    constexpr int IM = 2, KC = 32, TM = 128;
    constexpr int JF = TN / 16;
    constexpr int BLD = (TN * KC) / (4 * 256);

    __shared__ unsigned sB[KC * TN];

    const int tid = threadIdx.x;
    const int lane = tid & 63;
    const int wave = tid >> 6;
    const int l15 = lane & 15, l4 = lane >> 4;
    const int row0 = blockIdx.y * TM;
    const int col0 = blockIdx.x * TN;

    int bro[BLD], bgr[BLD];
    long bof[BLD];
    #pragma unroll
    for (int l = 0; l < BLD; ++l) {
        int idx = tid + 256 * l;
        bro[l] = idx % TN;
        bgr[l] = idx / TN;
        bof[l] = (long)(col0 + bro[l]) * K + bgr[l] * 4;
    }
    long aof[IM];
    #pragma unroll
    for (int i = 0; i < IM; ++i) {
        int r = row0 + wave * 32 + i * 16 + l15;
        if (r > M - 1) r = M - 1;
        aof[i] = (long)r * K + l4 * 8;
    }

    uint4 cB[BLD], nB[BLD], cA[IM][2], nA[IM][2];
    #pragma unroll
    for (int l = 0; l < BLD; ++l)
        cB[l] = *reinterpret_cast<const uint4*>(&Bp[bof[l]]);
    #pragma unroll
    for (int i = 0; i < IM; ++i) {
        cA[i][0] = *reinterpret_cast<const uint4*>(&A[aof[i]]);
        cA[i][1] = *reinterpret_cast<const uint4*>(&A[aof[i] + 4]);
    }

    f32x4 acc[IM][JF];
    #pragma unroll
    for (int i = 0; i < IM; ++i)
        #pragma unroll
        for (int j = 0; j < JF; ++j)
            acc[i][j] = (f32x4){0.f, 0.f, 0.f, 0.f};

    const int nc = K / KC;
    for (int c = 0; c < nc; ++c) {
        #pragma unroll
        for (int l = 0; l < BLD; ++l)
            *reinterpret_cast<uint4*>(&sB[(bgr[l] * TN + bro[l]) * 4]) = cB[l];
        __syncthreads();

        if (c + 1 < nc) {
            const int kc = (c + 1) * KC;
            #pragma unroll
            for (int l = 0; l < BLD; ++l)
                nB[l] = *reinterpret_cast<const uint4*>(&Bp[bof[l] + kc]);
            #pragma unroll
            for (int i = 0; i < IM; ++i) {
                nA[i][0] = *reinterpret_cast<const uint4*>(&A[aof[i] + kc]);
                nA[i][1] = *reinterpret_cast<const uint4*>(&A[aof[i] + kc + 4]);
            }
        }

        short8 ah[IM], al[IM];
        #pragma unroll
        for (int i = 0; i < IM; ++i)
            unpack_hl(cA[i][0], cA[i][1], ah[i], al[i]);

        #pragma unroll
        for (int j = 0; j < JF; ++j) {
            const int rowb = j * 16 + l15;
            uint4 b0 = *reinterpret_cast<const uint4*>(&sB[((2 * l4 + 0) * TN + rowb) * 4]);
            uint4 b1 = *reinterpret_cast<const uint4*>(&sB[((2 * l4 + 1) * TN + rowb) * 4]);
            short8 bh, bl;
            unpack_hl(b0, b1, bh, bl);
            #pragma unroll
            for (int i = 0; i < IM; ++i) {
                acc[i][j] = __builtin_amdgcn_mfma_f32_16x16x32_bf16(ah[i], bh, acc[i][j], 0, 0, 0);
                acc[i][j] = __builtin_amdgcn_mfma_f32_16x16x32_bf16(ah[i], bl, acc[i][j], 0, 0, 0);
                acc[i][j] = __builtin_amdgcn_mfma_f32_16x16x32_bf16(al[i], bh, acc[i][j], 0, 0, 0);
            }
        }
        __syncthreads();

        if (c + 1 < nc) {
            #pragma unroll
            for (int l = 0; l < BLD; ++l) cB[l] = nB[l];
            #pragma unroll
            for (int i = 0; i < IM; ++i) { cA[i][0] = nA[i][0]; cA[i][1] = nA[i][1]; }
        }
    }

    #pragma unroll
    for (int i = 0; i < IM; ++i) {
        const int rb = row0 + wave * 32 + i * 16 + l4 * 4;
        #pragma unroll
        for (int j = 0; j < JF; ++j) {
            const int col = col0 + j * 16 + l15;
            float bs = 0.0f;
            if (bias) bs = (bias2 && col >= 128) ? bias2[col - 128] : bias[col];
            #pragma unroll
            for (int g = 0; g < 4; ++g) {
                const int row = rb + g;
                if (row >= M) continue;
                float v = acc[i][j][g];
                if (rowscale) v *= rowscale[row];
                v += bs;
                if (RELU) v = fmaxf(v, 0.0f);
                if (outscale) v *= outscale[row];
                if (PACK_OUT) Cp[(long)row * N + col] = pack_hl(v);
                else          C[(long)row * N + col] = v;
            }
        }
    }
}

// Combined-heads final GEMM: A = tmpc [M,192] packed, B = wd1 [192,192]
// block-diag packed. cols 0..127 -> Cf+bf1; 128..191 -> Ce+be1.
__global__ __launch_bounds__(256) void mgemm_heads_kernel(
    const unsigned* __restrict__ A, const unsigned* __restrict__ Bp,
    const float* __restrict__ bf1, const float* __restrict__ be1,
    float* __restrict__ Cf, float* __restrict__ Ce, int M)
{
    constexpr int IM = 2, KC = 32, TM = 128, TN = 64, K = 192;
    constexpr int JF = TN / 16;
    constexpr int BLD = (TN * KC) / (4 * 256);

    __shared__ unsigned sB[KC * TN];

    const int tid = threadIdx.x;
    const int lane = tid & 63;
    const int wave = tid >> 6;
    const int l15 = lane & 15, l4 = lane >> 4;
    const int row0 = blockIdx.y * TM;
    const int col0 = blockIdx.x * TN;

    int bro[BLD], bgr[BLD];
    long bof[BLD];
    #pragma unroll
    for (int l = 0; l < BLD; ++l) {
        int idx = tid + 256 * l;
        bro[l] = idx % TN;
        bgr[l] = idx / TN;
        bof[l] = (long)(col0 + bro[l]) * K + bgr[l] * 4;
    }
    long aof[IM];
    #pragma unroll
    for (int i = 0; i < IM; ++i) {
        int r = row0 + wave * 32 + i * 16 + l15;
        if (r > M - 1) r = M - 1;
        aof[i] = (long)r * K + l4 * 8;
    }

    uint4 cB[BLD], nB[BLD], cA[IM][2], nA[IM][2];
    #pragma unroll
    for (int l = 0; l < BLD; ++l)
        cB[l] = *reinterpret_cast<const uint4*>(&Bp[bof[l]]);
    #pragma unroll
    for (int i = 0; i < IM; ++i) {
        cA[i][0] = *reinterpret_cast<const uint4*>(&A[aof[i]]);
        cA[i][1] = *reinterpret_cast<const uint4*>(&A[aof[i] + 4]);
    }

    f32x4 acc[IM][JF];
    #pragma unroll
    for (int i = 0; i < IM; ++i)
        #pragma unroll
        for (int j = 0; j < JF; ++j)
            acc[i][j] = (f32x4){0.f, 0.f, 0.f, 0.f};

    const int nc = K / KC;   // 6
    for (int c = 0; c < nc; ++c) {
        #pragma unroll
        for (int l = 0; l < BLD; ++l)
            *reinterpret_cast<uint4*>(&sB[(bgr[l] * TN + bro[l]) * 4]) = cB[l];
        __syncthreads();

        if (c + 1 < nc) {
            const int kc = (c + 1) * KC;
            #pragma unroll
            for (int l = 0; l < BLD; ++l)
                nB[l] = *reinterpret_cast<const uint4*>(&Bp[bof[l] + kc]);
            #pragma unroll
            for (int i = 0; i < IM; ++i) {
                nA[i][0] = *reinterpret_cast<const uint4*>(&A[aof[i] + kc]);
                nA[i][1] = *reinterpret_cast<const uint4*>(&A[aof[i] + kc + 4]);
            }
        }

        short8 ah[IM], al[IM];
        #pragma unroll
        for (int i = 0; i < IM; ++i)
            unpack_hl(cA[i][0], cA[i][1], ah[i], al[i]);

        #pragma unroll
        for (int j = 0; j < JF; ++j) {
            const int rowb = j * 16 + l15;
            uint4 b0 = *reinterpret_cast<const uint4*>(&sB[((2 * l4 + 0) * TN + rowb) * 4]);
            uint4 b1 = *reinterpret_cast<const uint4*>(&sB[((2 * l4 + 1) * TN + rowb) * 4]);
            short8 bh, bl;
            unpack_hl(b0, b1, bh, bl);
            #pragma unroll
            for (int i = 0; i < IM; ++i) {
                acc[i][j] = __builtin_amdgcn_mfma_f32_16x16x32_bf16(ah[i], bh, acc[i][j], 0, 0, 0);
                acc[i][j] = __builtin_amdgcn_mfma_f32_16x16x32_bf16(ah[i], bl, acc[i][j], 0, 0, 0);
                acc[i][j] = __builtin_amdgcn_mfma_f32_16x16x32_bf16(al[i], bh, acc[i][j], 0, 0, 0);
            }
        }
        __syncthreads();

        if (c + 1 < nc) {
            #pragma unroll
            for (int l = 0; l < BLD; ++l) cB[l] = nB[l];
            #pragma unroll
            for (int i = 0; i < IM; ++i) { cA[i][0] = nA[i][0]; cA[i][1] = nA[i][1]; }
        }
    }

    #pragma unroll
    for (int i = 0; i < IM; ++i) {
        const int rb = row0 + wave * 32 + i * 16 + l4 * 4;
        #pragma unroll
        for (int j = 0; j < JF; ++j) {
            const int col = col0 + j * 16 + l15;
            const bool isf = (col < 128);
            const float bs = isf ? bf1[col] : be1[col - 128];
            #pragma unroll
            for (int g = 0; g < 4; ++g) {
                const int row = rb + g;
                if (row >= M) continue;
                float v = acc[i][j][g] + bs;
                if (isf) Cf[(long)row * 128 + col] = v;
                else     Ce[(long)row * 64 + (col - 128)] = v;
            }
        }
    }
}

static inline long align8(long x) { return (x + 7) & ~7L; }

extern "C" void kernel_launch(void* const* d_in, const int* in_sizes, int n_in,
                              void* d_out, int out_size, void* d_ws, size_t ws_size,
                              hipStream_t stream)
{
    const float* features = (const float*)d_in[0];
    const int*   src      = (const int*)d_in[1];
    const int*   dst      = (const int*)d_in[2];
    const int*   trig     = (const int*)d_in[3];
    const float* W1  = (const float*)d_in[4];
    const float* b1  = (const float*)d_in[5];
    const float* W2  = (const float*)d_in[6];
    const float* b2  = (const float*)d_in[7];
    const float* Wf  = (const float*)d_in[8];
    const float* bf  = (const float*)d_in[9];
    const float* Wf1 = (const float*)d_in[10];
    const float* bf1 = (const float*)d_in[11];
    const float* We  = (const float*)d_in[12];
    const float* be  = (const float*)d_in[13];
    const float* We1 = (const float*)d_in[14];
    const float* be1 = (const float*)d_in[15];

    const int  d   = 128, h2d = 256, od = 64;
    const int  N   = in_sizes[0] / d;      // 50000
    const int  E   = in_sizes[1];          // 800000
    const int  T   = in_sizes[3];          // 4096
    const int  NB  = (N + 255) / 256;

    const int  HB    = 128;                 // histogram blocks (merge assumes 128)
    const int  chunk = (E + HB - 1) / HB;   // 6250
    const int  nhalf = (N + 1) / 2;         // 25000 (<= NHALF_CAP)

    // ---- workspace layout ----
    char* wsb = (char*)d_ws;
    long off = 0;  // bytes
    auto takeF = [&](long n) { float* p = (float*)(wsb + off); off += align8(n) * 4; return p; };
    auto takeI = [&](long n) { int*   p = (int*)  (wsb + off); off += align8(n) * 4; return p; };
    auto takeU = [&](long n) { unsigned* p = (unsigned*)(wsb + off); off += align8(n) * 4; return p; };

    float*    norm_out = takeF(N);
    float*    norm_in  = takeF(N);
    int*      deg_in   = takeI(N);
    int*      rowptr   = takeI(N + 1);
    int*      bsum     = takeI(256);
    int*      ecol     = takeI(E);
    unsigned* part_in  = takeU((long)HB * nhalf);   // 12.8 MB
    unsigned* part_out = takeU((long)HB * nhalf);   // 12.8 MB
    unsigned* agg1     = takeU((long)N * d);        // [N,128] packed
    unsigned* h1s      = takeU((long)N * h2d);      // [N,256] packed
    unsigned* agg2ts   = takeU((long)T * h2d);      // [T,256] packed (ni folded)
    unsigned* h2t      = takeU((long)T * d);        // [T,128] packed
    unsigned* tmpc     = takeU((long)T * 192);      // [T,192] packed (heads mid)
    unsigned* w1p      = takeU((long)h2d * d);      // [256,128]
    unsigned* w2p      = takeU((long)d * h2d);      // [128,256]
    unsigned* wc       = takeU(192L * d);           // [192,128] = [Wf^T; We^T]
    unsigned* wd1      = takeU(192L * 192);         // [192,192] block-diag

    float* out_feat = (float*)d_out;              // [T,128]
    float* out_edge = out_feat + (long)T * d;     // [T,64]

    // ---- weight transpose + pack (wd1 zero-padded block-diagonal) ----
    hipMemsetAsync(wd1, 0, 192L * 192 * sizeof(unsigned), stream);
    WPrep wp;
    wp.w[0] = W1;  wp.o[0] = w1p;              wp.K[0] = d;   wp.N[0] = h2d; wp.dstK[0] = d;
    wp.w[1] = W2;  wp.o[1] = w2p;              wp.K[1] = h2d; wp.N[1] = d;   wp.dstK[1] = h2d;
    wp.w[2] = Wf;  wp.o[2] = wc;               wp.K[2] = d;   wp.N[2] = d;   wp.dstK[2] = d;
    wp.w[3] = We;  wp.o[3] = wc + 128 * d;     wp.K[3] = d;   wp.N[3] = od;  wp.dstK[3] = d;
    wp.w[4] = Wf1; wp.o[4] = wd1;              wp.K[4] = d;   wp.N[4] = d;   wp.dstK[4] = 192;
    wp.w[5] = We1; wp.o[5] = wd1 + 128L * 192 + 128;
                                               wp.K[5] = od;  wp.N[5] = od;  wp.dstK[5] = 192;
    wp.base[0] = 0;
    for (int i = 0; i < 6; ++i) wp.base[i + 1] = wp.base[i] + wp.K[i] * wp.N[i];
    wprep_kernel<<<dim3((wp.base[6] + 255) / 256), dim3(256), 0, stream>>>(wp);

    // ---- CSR build (no fabric atomics, no memsets) ----
    hist_kernel<<<dim3(HB, 2), dim3(256), 0, stream>>>(
        src, dst, part_in, part_out, E, chunk, nhalf);
    merge_kernel<<<dim3((nhalf + 63) / 64), dim3(256), 0, stream>>>(
        part_in, part_out, deg_in, norm_in, norm_out, nhalf, N);
    scan1_kernel<<<dim3(NB), dim3(256), 0, stream>>>(deg_in, rowptr, bsum, N);
    scan2_kernel<<<dim3(1), dim3(256), 0, stream>>>(bsum, NB);
    scan3_kernel<<<dim3(NB), dim3(256), 0, stream>>>(rowptr, bsum, N);
    fill2_kernel<<<dim3(HB), dim3(256), 0, stream>>>(
        src, dst, rowptr, part_in, ecol, E, chunk, nhalf);

    const int GY = (N + 127) / 128;   // 391
    const int GT = T / 128;           // 32

    // ---- layer 1: agg1 = A@(features*no);  h1s = pack(relu(ni*agg1@W1+b1)*no)
    gather4_kernel<<<dim3((N + 3) / 4), dim3(256), 0, stream>>>(
        features, norm_out, rowptr, ecol, agg1, N);
    mgemm256_kernel<<<dim3(GY), dim3(256), 0, stream>>>(
        agg1, w1p, b1, norm_in, norm_out, h1s, N);

    // ---- layer 2 (gather-first): agg2ts = pack(ni * A@h1s at trig rows);
    //      h2t = pack(relu(agg2ts @ W2 + b2))
    gather_trig256_kernel<<<dim3((T + 3) / 4), dim3(256), 0, stream>>>(
        h1s, trig, norm_in, rowptr, ecol, agg2ts, T);
    mgemm_kernel<64, true, true><<<dim3(d / 64, GT), dim3(256), 0, stream>>>(
        agg2ts, w2p, b2, nullptr, nullptr, nullptr, nullptr, h2t, T, d, h2d);

    // ---- heads (combined): tmpc = pack(relu(h2t @ [Wf|We] + [bf|be]))
    mgemm_kernel<64, true, true><<<dim3(192 / 64, GT), dim3(256), 0, stream>>>(
        h2t, wc, bf, be, nullptr, nullptr, nullptr, tmpc, T, 192, d);
    // [out_feat|out_edge] = tmpc @ blockdiag(Wf1, We1) + [bf1|be1]
    mgemm_heads_kernel<<<dim3(3, GT), dim3(256), 0, stream>>>(
        tmpc, wd1, bf1, be1, out_feat, out_edge, T);
}